// Round 15
// baseline (135.181 us; speedup 1.0000x reference)
//
#include <hip/hip_runtime.h>
#include <hip/hip_bf16.h>
#include <stdint.h>

#define B_DIM 32
#define I_DIM 2048
#define J_DIM 2048
#define K_DIM 128

typedef __attribute__((ext_vector_type(8))) short bf16x8;
typedef __attribute__((ext_vector_type(4))) short short4v;
typedef __attribute__((ext_vector_type(4))) float f32x4;

__device__ inline short f2bf(float f) {
  union { float f; uint32_t u; } v; v.f = f;
  uint32_t u = v.u + 0x7fffu + ((v.u >> 16) & 1u);  // RNE
  return (short)(u >> 16);
}

// ---------------- pass 1: B fp32 [b][k][j] -> Bt bf16 [b][j][k], register transpose ----------------
// Thread (j = t&63, ks = t>>6): 32 scalar reads B[ks*32+e][j] (each inst = 256B
// coalesced across the wave's 64 consecutive j), cvt in-register, write 64B
// contiguous Bt[j][ks*32..+31] as 4 x 16B. No LDS, no syncthreads. Each 128B Bt
// line is completed by two co-resident waves (ks pairs) -> L2 write-merge.
__global__ __launch_bounds__(256) void transB_kernel(const float* __restrict__ B,
                                                     short* __restrict__ Bt) {
  const int t  = threadIdx.x;
  const int j0 = blockIdx.x * 64;
  const int b  = blockIdx.y;
  const int j  = j0 + (t & 63);
  const int ks = t >> 6;                       // 0..3 (k-strip of 32)
  const float* src = B + (size_t)b * K_DIM * J_DIM + (size_t)(ks * 32) * J_DIM + j;
  bf16x8 o[4];
  #pragma unroll
  for (int g = 0; g < 4; ++g)
    #pragma unroll
    for (int e = 0; e < 8; ++e)
      o[g][e] = f2bf(src[(size_t)(g * 8 + e) * J_DIM]);
  short* dst = Bt + (size_t)b * J_DIM * K_DIM + (size_t)j * K_DIM + ks * 32;
  #pragma unroll
  for (int g = 0; g < 4; ++g)
    reinterpret_cast<bf16x8*>(dst)[g] = o[g];
}

// ---------------- pass 2: persistent 4-tile GEMM + in-prologue A conversion (R14 champion) ----
#define GLD_LDS16(g, l) __builtin_amdgcn_global_load_lds( \
    (const __attribute__((address_space(1))) uint32_t*)(g), \
    (__attribute__((address_space(3))) uint32_t*)(l), 16, 0, 0)

__global__ __launch_bounds__(256, 2) void gemm_kernel(const float* __restrict__ A,
                                                      const short* __restrict__ Bt,
                                                      float* __restrict__ C) {
  __shared__ __align__(16) short As[128 * 128];   // 32 KB bf16, whole K, swizzled
  __shared__ __align__(16) short Bs[128 * 128];   // 32 KB bf16, whole K, swizzled
  const int t = threadIdx.x;
  const int p = blockIdx.x;
  const int jg = p & 3, it = (p >> 2) & 15, b = p >> 6;

  const int w = t >> 6, wm = w >> 1, wn = w & 1;
  const int lane = t & 63, lr = lane & 15, g = lane >> 4;

  // B staging (global_load_lds): inst i covers rows 16i..16i+15; thread t -> row t>>4,
  // dest slot t&15, source slot (t&15)^(row&15) (pre-swizzled source, rule 21)
  const int srow  = t >> 4;
  const int sbyte = ((t & 15) ^ srow) << 4;
  const char* Bbase = (const char*)(Bt + ((size_t)b * J_DIM + srow) * K_DIM) + sbyte;
  char* Bdst = (char*)Bs + w * 1024;              // wave-uniform base; HW adds lane*16

  // ---- prologue: stage B tile jt=jg*4 (DMA) + convert A panel fp32->bf16 into As ----
  {
    const char* Bsrc = Bbase + (size_t)(jg * 4) * 32768;
    #pragma unroll
    for (int i = 0; i < 8; ++i) GLD_LDS16(Bsrc + i * 4096, Bdst + i * 4096);
  }
  {
    // A panel: 128 rows x 512B fp32. 32B pair-index pp = t + j*256:
    // row = pp>>4, granule g0 = pp&15 (16B bf16 granule holds k-slot g0^(row&15)).
    const float* Apan = A + ((size_t)b * I_DIM + it * 128) * K_DIM;
    #pragma unroll
    for (int j = 0; j < 8; ++j) {
      const int pp  = t + j * 256;
      const int row = pp >> 4, g0 = pp & 15;
      const f32x4 lo = *reinterpret_cast<const f32x4*>(Apan + (size_t)pp * 8);
      const f32x4 hi = *reinterpret_cast<const f32x4*>(Apan + (size_t)pp * 8 + 4);
      bf16x8 o;
      o[0] = f2bf(lo[0]); o[1] = f2bf(lo[1]); o[2] = f2bf(lo[2]); o[3] = f2bf(lo[3]);
      o[4] = f2bf(hi[0]); o[5] = f2bf(hi[1]); o[6] = f2bf(hi[2]); o[7] = f2bf(hi[3]);
      *reinterpret_cast<bf16x8*>((char*)As + row * 256 + ((g0 ^ (row & 15)) << 4)) = o;
    }
  }
  asm volatile("s_waitcnt vmcnt(0) lgkmcnt(0)" ::: "memory");
  __builtin_amdgcn_sched_barrier(0);
  __builtin_amdgcn_s_barrier();
  __builtin_amdgcn_sched_barrier(0);

  float* Cb = C + (size_t)b * I_DIM * J_DIM;

  #pragma unroll 1
  for (int q = 0; q < 4; ++q) {
    const int jt = jg * 4 + q;

    f32x4 acc[4][4];
    #pragma unroll
    for (int m = 0; m < 4; ++m)
      #pragma unroll
      for (int n = 0; n < 4; ++n)
        acc[m][n] = (f32x4){0.f, 0.f, 0.f, 0.f};

    #pragma unroll
    for (int kg = 0; kg < 4; ++kg) {            // K = 4 x 32
      const int sl = kg * 4 + g;                // global k-slot (16B units)
      bf16x8 af[4], bb[4];
      #pragma unroll
      for (int m = 0; m < 4; ++m) {
        const int R = wm * 64 + m * 16 + lr;
        af[m] = *reinterpret_cast<const bf16x8*>((const char*)As + R * 256 + ((sl ^ lr) << 4));
      }
      #pragma unroll
      for (int n = 0; n < 4; ++n) {
        const int R = wn * 64 + n * 16 + lr;
        bb[n] = *reinterpret_cast<const bf16x8*>((const char*)Bs + R * 256 + ((sl ^ lr) << 4));
      }
      #pragma unroll
      for (int m = 0; m < 4; ++m)
        #pragma unroll
        for (int n = 0; n < 4; ++n)
          acc[m][n] = __builtin_amdgcn_mfma_f32_16x16x32_bf16(af[m], bb[n], acc[m][n], 0, 0, 0);
    }

    // all waves' Bs reads consumed (each wave's lgkmcnt enforced before its MFMAs)
    __builtin_amdgcn_s_barrier();
    __builtin_amdgcn_sched_barrier(0);

    if (q < 3) {                                // stage next B (oldest in VM queue)
      const char* Bsrc = Bbase + (size_t)(jt + 1) * 32768;
      #pragma unroll
      for (int i = 0; i < 8; ++i) GLD_LDS16(Bsrc + i * 4096, Bdst + i * 4096);
    }

    // issue C stores for tile q (fire-and-forget; drain overlaps next tile)
    const int cbase = jt * 128 + wn * 64 + lr;
    #pragma unroll
    for (int m = 0; m < 4; ++m) {
      const int rbase = it * 128 + wm * 64 + m * 16 + g * 4;
      #pragma unroll
      for (int qq = 0; qq < 4; ++qq) {
        float* crow = Cb + (size_t)(rbase + qq) * J_DIM + cbase;
        #pragma unroll
        for (int n = 0; n < 4; ++n) crow[n * 16] = acc[m][n][qq];
      }
    }

    if (q < 3) {
      // loads are older than the 64 new stores: vmcnt(63) guarantees the loads
      // landed while leaving ~63 stores in flight.
      asm volatile("s_waitcnt vmcnt(63)" ::: "memory");
      __builtin_amdgcn_sched_barrier(0);
      __builtin_amdgcn_s_barrier();
      __builtin_amdgcn_sched_barrier(0);
    }
  }
}

// ---------------- fallback (used only if ws too small) ----------------
__device__ inline int swz_fb(int row, int kbyte) {
  return row * 128 + ((kbyte ^ ((row & 15) << 4)) >> 1);
}

__global__ __launch_bounds__(256, 2) void bmm_fallback(const float* __restrict__ A,
                                                       const float* __restrict__ Bm,
                                                       float* __restrict__ C) {
  __shared__ short As[128 * 128];
  __shared__ short Bs[128 * 128];
  const int t  = threadIdx.x;
  const int jt = blockIdx.x, it = blockIdx.y, b = blockIdx.z;
  const float* Abp = A  + (size_t)b * I_DIM * K_DIM;
  const float* Bbp = Bm + (size_t)b * K_DIM * J_DIM;
  {
    const int r0 = t >> 5;
    const int k0 = (t & 31) * 4;
    #pragma unroll 4
    for (int i8 = 0; i8 < 16; ++i8) {
      const int r = i8 * 8 + r0;
      const float4 v = *reinterpret_cast<const float4*>(
          Abp + (size_t)(it * 128 + r) * K_DIM + k0);
      short4v s; s.x = f2bf(v.x); s.y = f2bf(v.y); s.z = f2bf(v.z); s.w = f2bf(v.w);
      *reinterpret_cast<short4v*>(&As[swz_fb(r, 2 * k0)]) = s;
    }
  }
  {
    const int j  = t & 127;
    const int kq = (t >> 7) * 4;
    #pragma unroll 4
    for (int kb = 0; kb < 16; ++kb) {
      const int k0 = kb * 8 + kq;
      const float* p = Bbp + (size_t)k0 * J_DIM + jt * 128 + j;
      const float f0 = p[0], f1 = p[J_DIM], f2 = p[2 * J_DIM], f3 = p[3 * J_DIM];
      short4v s; s.x = f2bf(f0); s.y = f2bf(f1); s.z = f2bf(f2); s.w = f2bf(f3);
      *reinterpret_cast<short4v*>(&Bs[swz_fb(j, 2 * k0)]) = s;
    }
  }
  __syncthreads();
  const int w = t >> 6, wm = w >> 1, wn = w & 1;
  const int lane = t & 63, lr = lane & 15, g = lane >> 4;
  f32x4 acc[4][4];
  #pragma unroll
  for (int m = 0; m < 4; ++m)
    #pragma unroll
    for (int n = 0; n < 4; ++n) acc[m][n] = (f32x4){0.f, 0.f, 0.f, 0.f};
  #pragma unroll
  for (int kk = 0; kk < 4; ++kk) {
    bf16x8 af[4], bfr[4];
    const int kb = kk * 64 + g * 16;
    #pragma unroll
    for (int m = 0; m < 4; ++m) {
      const int r = wm * 64 + m * 16 + lr;
      af[m] = *reinterpret_cast<const bf16x8*>(&As[swz_fb(r, kb)]);
    }
    #pragma unroll
    for (int n = 0; n < 4; ++n) {
      const int r = wn * 64 + n * 16 + lr;
      bfr[n] = *reinterpret_cast<const bf16x8*>(&Bs[swz_fb(r, kb)]);
    }
    #pragma unroll
    for (int m = 0; m < 4; ++m)
      #pragma unroll
      for (int n = 0; n < 4; ++n)
        acc[m][n] = __builtin_amdgcn_mfma_f32_16x16x32_bf16(af[m], bfr[n], acc[m][n], 0, 0, 0);
  }
  float* Cb = C + (size_t)b * I_DIM * J_DIM;
  const int cbase = jt * 128 + wn * 64 + lr;
  #pragma unroll
  for (int m = 0; m < 4; ++m) {
    const int rbase = it * 128 + wm * 64 + m * 16 + g * 4;
    #pragma unroll
    for (int q = 0; q < 4; ++q) {
      float* crow = Cb + (size_t)(rbase + q) * J_DIM + cbase;
      #pragma unroll
      for (int n = 0; n < 4; ++n) crow[n * 16] = acc[m][n][q];
    }
  }
}

extern "C" void kernel_launch(void* const* d_in, const int* in_sizes, int n_in,
                              void* d_out, int out_size, void* d_ws, size_t ws_size,
                              hipStream_t stream) {
  const float* A  = (const float*)d_in[0];
  const float* Bm = (const float*)d_in[1];
  float* C = (float*)d_out;
  const size_t needB = (size_t)B_DIM * K_DIM * J_DIM * sizeof(short);  // 16 MiB
  if (ws_size >= needB) {
    short* Bt = (short*)d_ws;
    transB_kernel<<<dim3(J_DIM / 64, B_DIM), 256, 0, stream>>>(Bm, Bt);
    gemm_kernel<<<2048, 256, 0, stream>>>(A, Bt, C);   // 32b x 16it x 4jg, 4 jt each
  } else {
    bmm_fallback<<<dim3(J_DIM / 128, I_DIM / 128, B_DIM), 256, 0, stream>>>(A, Bm, C);
  }
}

// Round 16
// 132.874 us; speedup vs baseline: 1.0174x; 1.0174x over previous
//
#include <hip/hip_runtime.h>
#include <hip/hip_bf16.h>
#include <stdint.h>

#define B_DIM 32
#define I_DIM 2048
#define J_DIM 2048
#define K_DIM 128

typedef __attribute__((ext_vector_type(8))) short bf16x8;
typedef __attribute__((ext_vector_type(4))) short short4v;
typedef __attribute__((ext_vector_type(4))) float f32x4;

__device__ inline short f2bf(float f) {
  union { float f; uint32_t u; } v; v.f = f;
  uint32_t u = v.u + 0x7fffu + ((v.u >> 16) & 1u);  // RNE
  return (short)(u >> 16);
}

// ---------------- pass 1: B fp32 [b][k][j] -> Bt bf16 [b][j][k] (float4 reads, LDS transpose) ----
__global__ __launch_bounds__(256) void transB_kernel(const float* __restrict__ B,
                                                     short* __restrict__ Bt) {
  __shared__ __align__(16) short tile[64 * 128];
  const int t  = threadIdx.x;
  const int j0 = blockIdx.x * 64;
  const int b  = blockIdx.y;
  const float* Bb = B + (size_t)b * K_DIM * J_DIM;
  const int qj = t & 15;          // j-quad within 64
  const int k0 = t >> 4;          // 0..15
  #pragma unroll
  for (int kp = 0; kp < 8; ++kp) {
    const int k = kp * 16 + k0;
    const f32x4 v = *reinterpret_cast<const f32x4*>(Bb + (size_t)k * J_DIM + j0 + 4 * qj);
    #pragma unroll
    for (int e = 0; e < 4; ++e) {
      const int jj = 4 * qj + e;
      tile[jj * 128 + (k ^ ((jj & 15) << 3))] = f2bf(v[e]);
    }
  }
  __syncthreads();
  short* Btb = Bt + (size_t)b * J_DIM * K_DIM;
  const int slot = t & 15, jr = t >> 4;
  #pragma unroll
  for (int r2 = 0; r2 < 4; ++r2) {
    const int j  = r2 * 16 + jr;
    const bf16x8 v = *reinterpret_cast<const bf16x8*>(&tile[j * 128 + slot * 8]);
    const int kk0 = (slot * 8) ^ ((j & 15) << 3);
    *reinterpret_cast<bf16x8*>(Btb + (size_t)(j0 + j) * K_DIM + kk0) = v;
  }
}

// ---------------- pass 2: persistent 4-tile GEMM + in-prologue A conversion (R14 champion) ----
#define GLD_LDS16(g, l) __builtin_amdgcn_global_load_lds( \
    (const __attribute__((address_space(1))) uint32_t*)(g), \
    (__attribute__((address_space(3))) uint32_t*)(l), 16, 0, 0)

__global__ __launch_bounds__(256, 2) void gemm_kernel(const float* __restrict__ A,
                                                      const short* __restrict__ Bt,
                                                      float* __restrict__ C) {
  __shared__ __align__(16) short As[128 * 128];   // 32 KB bf16, whole K, swizzled
  __shared__ __align__(16) short Bs[128 * 128];   // 32 KB bf16, whole K, swizzled
  const int t = threadIdx.x;
  const int p = blockIdx.x;
  const int jg = p & 3, it = (p >> 2) & 15, b = p >> 6;

  const int w = t >> 6, wm = w >> 1, wn = w & 1;
  const int lane = t & 63, lr = lane & 15, g = lane >> 4;

  // B staging (global_load_lds): inst i covers rows 16i..16i+15; thread t -> row t>>4,
  // dest slot t&15, source slot (t&15)^(row&15) (pre-swizzled source, rule 21)
  const int srow  = t >> 4;
  const int sbyte = ((t & 15) ^ srow) << 4;
  const char* Bbase = (const char*)(Bt + ((size_t)b * J_DIM + srow) * K_DIM) + sbyte;
  char* Bdst = (char*)Bs + w * 1024;              // wave-uniform base; HW adds lane*16

  // ---- prologue: stage B tile jt=jg*4 (DMA) + convert A panel fp32->bf16 into As ----
  {
    const char* Bsrc = Bbase + (size_t)(jg * 4) * 32768;
    #pragma unroll
    for (int i = 0; i < 8; ++i) GLD_LDS16(Bsrc + i * 4096, Bdst + i * 4096);
  }
  {
    // A panel: 128 rows x 512B fp32. 32B pair-index pp = t + j*256:
    // row = pp>>4, granule g0 = pp&15 (16B bf16 granule holds k-slot g0^(row&15)).
    const float* Apan = A + ((size_t)b * I_DIM + it * 128) * K_DIM;
    #pragma unroll
    for (int j = 0; j < 8; ++j) {
      const int pp  = t + j * 256;
      const int row = pp >> 4, g0 = pp & 15;
      const f32x4 lo = *reinterpret_cast<const f32x4*>(Apan + (size_t)pp * 8);
      const f32x4 hi = *reinterpret_cast<const f32x4*>(Apan + (size_t)pp * 8 + 4);
      bf16x8 o;
      o[0] = f2bf(lo[0]); o[1] = f2bf(lo[1]); o[2] = f2bf(lo[2]); o[3] = f2bf(lo[3]);
      o[4] = f2bf(hi[0]); o[5] = f2bf(hi[1]); o[6] = f2bf(hi[2]); o[7] = f2bf(hi[3]);
      *reinterpret_cast<bf16x8*>((char*)As + row * 256 + ((g0 ^ (row & 15)) << 4)) = o;
    }
  }
  asm volatile("s_waitcnt vmcnt(0) lgkmcnt(0)" ::: "memory");
  __builtin_amdgcn_sched_barrier(0);
  __builtin_amdgcn_s_barrier();
  __builtin_amdgcn_sched_barrier(0);

  float* Cb = C + (size_t)b * I_DIM * J_DIM;

  #pragma unroll 1
  for (int q = 0; q < 4; ++q) {
    const int jt = jg * 4 + q;

    f32x4 acc[4][4];
    #pragma unroll
    for (int m = 0; m < 4; ++m)
      #pragma unroll
      for (int n = 0; n < 4; ++n)
        acc[m][n] = (f32x4){0.f, 0.f, 0.f, 0.f};

    #pragma unroll
    for (int kg = 0; kg < 4; ++kg) {            // K = 4 x 32
      const int sl = kg * 4 + g;                // global k-slot (16B units)
      bf16x8 af[4], bb[4];
      #pragma unroll
      for (int m = 0; m < 4; ++m) {
        const int R = wm * 64 + m * 16 + lr;
        af[m] = *reinterpret_cast<const bf16x8*>((const char*)As + R * 256 + ((sl ^ lr) << 4));
      }
      #pragma unroll
      for (int n = 0; n < 4; ++n) {
        const int R = wn * 64 + n * 16 + lr;
        bb[n] = *reinterpret_cast<const bf16x8*>((const char*)Bs + R * 256 + ((sl ^ lr) << 4));
      }
      #pragma unroll
      for (int m = 0; m < 4; ++m)
        #pragma unroll
        for (int n = 0; n < 4; ++n)
          acc[m][n] = __builtin_amdgcn_mfma_f32_16x16x32_bf16(af[m], bb[n], acc[m][n], 0, 0, 0);
    }

    // all waves' Bs reads consumed (each wave's lgkmcnt enforced before its MFMAs)
    __builtin_amdgcn_s_barrier();
    __builtin_amdgcn_sched_barrier(0);

    if (q < 3) {                                // stage next B (oldest in VM queue)
      const char* Bsrc = Bbase + (size_t)(jt + 1) * 32768;
      #pragma unroll
      for (int i = 0; i < 8; ++i) GLD_LDS16(Bsrc + i * 4096, Bdst + i * 4096);
    }

    // issue C stores for tile q (fire-and-forget; drain overlaps next tile)
    const int cbase = jt * 128 + wn * 64 + lr;
    #pragma unroll
    for (int m = 0; m < 4; ++m) {
      const int rbase = it * 128 + wm * 64 + m * 16 + g * 4;
      #pragma unroll
      for (int qq = 0; qq < 4; ++qq) {
        float* crow = Cb + (size_t)(rbase + qq) * J_DIM + cbase;
        #pragma unroll
        for (int n = 0; n < 4; ++n) crow[n * 16] = acc[m][n][qq];
      }
    }

    if (q < 3) {
      // loads are older than the 64 new stores: vmcnt(63) guarantees the loads
      // landed while leaving ~63 stores in flight.
      asm volatile("s_waitcnt vmcnt(63)" ::: "memory");
      __builtin_amdgcn_sched_barrier(0);
      __builtin_amdgcn_s_barrier();
      __builtin_amdgcn_sched_barrier(0);
    }
  }
}

// ---------------- fallback (used only if ws too small) ----------------
__device__ inline int swz_fb(int row, int kbyte) {
  return row * 128 + ((kbyte ^ ((row & 15) << 4)) >> 1);
}

__global__ __launch_bounds__(256, 2) void bmm_fallback(const float* __restrict__ A,
                                                       const float* __restrict__ Bm,
                                                       float* __restrict__ C) {
  __shared__ short As[128 * 128];
  __shared__ short Bs[128 * 128];
  const int t  = threadIdx.x;
  const int jt = blockIdx.x, it = blockIdx.y, b = blockIdx.z;
  const float* Abp = A  + (size_t)b * I_DIM * K_DIM;
  const float* Bbp = Bm + (size_t)b * K_DIM * J_DIM;
  {
    const int r0 = t >> 5;
    const int k0 = (t & 31) * 4;
    #pragma unroll 4
    for (int i8 = 0; i8 < 16; ++i8) {
      const int r = i8 * 8 + r0;
      const float4 v = *reinterpret_cast<const float4*>(
          Abp + (size_t)(it * 128 + r) * K_DIM + k0);
      short4v s; s.x = f2bf(v.x); s.y = f2bf(v.y); s.z = f2bf(v.z); s.w = f2bf(v.w);
      *reinterpret_cast<short4v*>(&As[swz_fb(r, 2 * k0)]) = s;
    }
  }
  {
    const int j  = t & 127;
    const int kq = (t >> 7) * 4;
    #pragma unroll 4
    for (int kb = 0; kb < 16; ++kb) {
      const int k0 = kb * 8 + kq;
      const float* p = Bbp + (size_t)k0 * J_DIM + jt * 128 + j;
      const float f0 = p[0], f1 = p[J_DIM], f2 = p[2 * J_DIM], f3 = p[3 * J_DIM];
      short4v s; s.x = f2bf(f0); s.y = f2bf(f1); s.z = f2bf(f2); s.w = f2bf(f3);
      *reinterpret_cast<short4v*>(&Bs[swz_fb(j, 2 * k0)]) = s;
    }
  }
  __syncthreads();
  const int w = t >> 6, wm = w >> 1, wn = w & 1;
  const int lane = t & 63, lr = lane & 15, g = lane >> 4;
  f32x4 acc[4][4];
  #pragma unroll
  for (int m = 0; m < 4; ++m)
    #pragma unroll
    for (int n = 0; n < 4; ++n) acc[m][n] = (f32x4){0.f, 0.f, 0.f, 0.f};
  #pragma unroll
  for (int kk = 0; kk < 4; ++kk) {
    bf16x8 af[4], bfr[4];
    const int kb = kk * 64 + g * 16;
    #pragma unroll
    for (int m = 0; m < 4; ++m) {
      const int r = wm * 64 + m * 16 + lr;
      af[m] = *reinterpret_cast<const bf16x8*>(&As[swz_fb(r, kb)]);
    }
    #pragma unroll
    for (int n = 0; n < 4; ++n) {
      const int r = wn * 64 + n * 16 + lr;
      bfr[n] = *reinterpret_cast<const bf16x8*>(&Bs[swz_fb(r, kb)]);
    }
    #pragma unroll
    for (int m = 0; m < 4; ++m)
      #pragma unroll
      for (int n = 0; n < 4; ++n)
        acc[m][n] = __builtin_amdgcn_mfma_f32_16x16x32_bf16(af[m], bfr[n], acc[m][n], 0, 0, 0);
  }
  float* Cb = C + (size_t)b * I_DIM * J_DIM;
  const int cbase = jt * 128 + wn * 64 + lr;
  #pragma unroll
  for (int m = 0; m < 4; ++m) {
    const int rbase = it * 128 + wm * 64 + m * 16 + g * 4;
    #pragma unroll
    for (int q = 0; q < 4; ++q) {
      float* crow = Cb + (size_t)(rbase + q) * J_DIM + cbase;
      #pragma unroll
      for (int n = 0; n < 4; ++n) crow[n * 16] = acc[m][n][q];
    }
  }
}

extern "C" void kernel_launch(void* const* d_in, const int* in_sizes, int n_in,
                              void* d_out, int out_size, void* d_ws, size_t ws_size,
                              hipStream_t stream) {
  const float* A  = (const float*)d_in[0];
  const float* Bm = (const float*)d_in[1];
  float* C = (float*)d_out;
  const size_t needB = (size_t)B_DIM * K_DIM * J_DIM * sizeof(short);  // 16 MiB
  if (ws_size >= needB) {
    short* Bt = (short*)d_ws;
    transB_kernel<<<dim3(J_DIM / 64, B_DIM), 256, 0, stream>>>(Bm, Bt);
    gemm_kernel<<<2048, 256, 0, stream>>>(A, Bt, C);   // 32b x 16it x 4jg, 4 jt each
  } else {
    bmm_fallback<<<dim3(J_DIM / 128, I_DIM / 128, B_DIM), 256, 0, stream>>>(A, Bm, C);
  }
}